// Round 1
// baseline (872.965 us; speedup 1.0000x reference)
//
#include <hip/hip_runtime.h>

#define SEQ 14
#define EMB 64
#define NBC (1024*64)      // B*C = 65536
#define XTILE (SEQ*EMB)    // 896 floats per (b,c) tile
#define LN_EPS 1e-5f
#define WAVES 4
#define XSTR 68            // padded LDS row stride (68*4B = 272B, 16B-aligned, conflict-free)

// ---------------------------------------------------------------------------
// prep: M[d][e] = sum_t Wq[t][d]*Wk[t][e]   (so energy = x M x^T + ...)
//       WvT[d][e] = Wv[e][d]
//       r[e] = sum_t bq[t]*Wk[t][e]         (bk-terms cancel under LayerNorm)
// ws layout (floats): interleaved MW[d][e] = (M, WvT) pairs: 64*64*2 = 8192,
//                     then r at [8192..8255]
// ---------------------------------------------------------------------------
__global__ void prep_kernel(const float* __restrict__ Wq, const float* __restrict__ Wk,
                            const float* __restrict__ Wv, const float* __restrict__ bq,
                            float* __restrict__ ws) {
    int d = blockIdx.x;    // 0..63
    int e = threadIdx.x;   // 0..63
    float m = 0.f, r = 0.f;
#pragma unroll 8
    for (int t = 0; t < 64; ++t) {
        float wk = Wk[t*64 + e];
        m = fmaf(Wq[t*64 + d], wk, m);
        r = fmaf(bq[t], wk, r);
    }
    ws[d*128 + 2*e]     = m;               // M[d][e]
    ws[d*128 + 2*e + 1] = Wv[e*64 + d];    // WvT[d][e]
    if (d == 0) ws[8192 + e] = r;
}

// ---------------------------------------------------------------------------
// main: one wave per (b,c) pair, grid-stride. No block barriers in hot loop.
// ---------------------------------------------------------------------------
__global__ __launch_bounds__(256, 4)
void attn_kernel(const float* __restrict__ x, const float* __restrict__ wc,
                 const float* __restrict__ bv, const float* __restrict__ lng,
                 const float* __restrict__ lnb, const float* __restrict__ ws,
                 float* __restrict__ out) {
    __shared__ __align__(16) float Lwc[14*16];          // w_c rows, stride 16, zero-padded
    __shared__ __align__(16) float Lln[2*16];           // ln_g, ln_b
    __shared__ __align__(16) float LxW[WAVES][SEQ*XSTR]; // per-wave x tile [q][d]
    __shared__ __align__(16) float LgW[WAVES][SEQ*XSTR]; // per-wave g tile [a][d]
    __shared__ __align__(16) float LeW[WAVES][SEQ*16];   // per-wave energy1/att [a][l]

    int tid = threadIdx.x;
    if (tid < 224) {
        int a = tid >> 4, m = tid & 15;
        Lwc[tid] = (m < 14) ? wc[a*14 + m] : 0.f;
    }
    if (tid < 16) {
        Lln[tid]      = (tid < 14) ? lng[tid] : 0.f;
        Lln[16 + tid] = (tid < 14) ? lnb[tid] : 0.f;
    }
    __syncthreads();

    int lane = tid & 63;
    int wv   = __builtin_amdgcn_readfirstlane(tid >> 6);
    int wv0  = blockIdx.x * WAVES + wv;
    const int TW = gridDim.x * WAVES;

    float rv  = ws[8192 + lane];   // r[e], init for t'
    float bvv = bv[lane];          // bias for v
    const float2* __restrict__ MW = (const float2*)ws;

    float* xw = &LxW[wv][0];
    float* gw = &LgW[wv][0];
    float* ew = &LeW[wv][0];

    for (int bc = wv0; bc < NBC; bc += TW) {
        const float* __restrict__ xb = x + (size_t)bc * XTILE;

        // ---- stage x tile into LDS (padded [q][d], for phase C) ----
        {
            const float4* xb4 = (const float4*)xb;
            int i0 = lane, i1 = 64 + lane, i2 = 128 + lane;
            float4 v0 = xb4[i0];
            float4 v1 = xb4[i1];
            float4 v2 = xb4[i2];
            *(float4*)(xw + (i0 >> 4)*XSTR + (i0 & 15)*4) = v0;
            *(float4*)(xw + (i1 >> 4)*XSTR + (i1 & 15)*4) = v1;
            *(float4*)(xw + (i2 >> 4)*XSTR + (i2 & 15)*4) = v2;
            if (lane < 32) {
                int i3 = 192 + lane;
                float4 v3 = xb4[i3];
                *(float4*)(xw + (i3 >> 4)*XSTR + (i3 & 15)*4) = v3;
            }
        }

        // ---- phase A: fused GEMMs  t'[i][lane] = x[i][:]·M[:][lane] + r
        //                            v [i][lane] = x[i][:]·WvT[:][lane] + bv ----
        float tc[SEQ], vcr[SEQ];
#pragma unroll
        for (int i = 0; i < SEQ; ++i) { tc[i] = rv; vcr[i] = bvv; }

        for (int d0 = 0; d0 < 16; ++d0) {
            float4 xs4[SEQ];
#pragma unroll
            for (int i = 0; i < SEQ; ++i)
                xs4[i] = *(const float4*)(xb + i*EMB + d0*4);   // wave-uniform -> s_load
#pragma unroll
            for (int j = 0; j < 4; ++j) {
                float2 mw = MW[(d0*4 + j)*64 + lane];
#pragma unroll
                for (int i = 0; i < SEQ; ++i) {
                    float xv = ((const float*)&xs4[i])[j];
                    tc[i]  = fmaf(xv, mw.x, tc[i]);
                    vcr[i] = fmaf(xv, mw.y, vcr[i]);
                }
            }
        }

        // ---- phase B: fold w_c mix:  g[a][lane] = sum_m wc[a][m]*t'[m][lane] ----
#pragma unroll
        for (int a = 0; a < SEQ; ++a) {
            float acc = 0.f;
#pragma unroll
            for (int m = 0; m < SEQ; ++m)
                acc = fmaf(Lwc[a*16 + m], tc[m], acc);  // broadcast LDS read
            gw[a*XSTR + lane] = acc;
        }

        // ---- phase C: energy1[a][l] = g[a][:]·x[l][:]  (196 dots, ~3 per lane) ----
#pragma unroll
        for (int k = 0; k < 4; ++k) {
            int p = lane + 64*k;
            if (p < 196) {
                int a = p / 14, l = p % 14;
                float acc = 0.f;
#pragma unroll
                for (int d = 0; d < 64; d += 4) {
                    float4 g4 = *(const float4*)(gw + a*XSTR + d);
                    float4 x4 = *(const float4*)(xw + l*XSTR + d);
                    acc = fmaf(g4.x, x4.x, acc);
                    acc = fmaf(g4.y, x4.y, acc);
                    acc = fmaf(g4.z, x4.z, acc);
                    acc = fmaf(g4.w, x4.w, acc);
                }
                ew[a*16 + l] = acc;
            }
        }

        // ---- phase D: LayerNorm(14) + softmax per row (lane a < 14) ----
        if (lane < SEQ) {
            float ev[SEQ];
            float mu = 0.f;
#pragma unroll
            for (int l = 0; l < SEQ; ++l) { ev[l] = ew[lane*16 + l]; mu += ev[l]; }
            mu *= (1.f/14.f);
            float var = 0.f;
#pragma unroll
            for (int l = 0; l < SEQ; ++l) { float d = ev[l] - mu; var = fmaf(d, d, var); }
            var *= (1.f/14.f);
            float inv = rsqrtf(var + LN_EPS);
            float zmax = -1e30f;
#pragma unroll
            for (int l = 0; l < SEQ; ++l) {
                float z = fmaf((ev[l] - mu) * inv, Lln[l], Lln[16 + l]) * 0.125f; // /sqrt(64)
                ev[l] = z;
                zmax = fmaxf(zmax, z);
            }
            float s = 0.f;
#pragma unroll
            for (int l = 0; l < SEQ; ++l) { float e = __expf(ev[l] - zmax); ev[l] = e; s += e; }
            float rs = 1.f / s;
#pragma unroll
            for (int l = 0; l < SEQ; ++l) ew[lane*16 + l] = ev[l] * rs;
        }

        // ---- phase E: out[a][lane] = sum_l att[a][l] * v[l][lane] ----
        float* outb = out + (size_t)bc * XTILE;
#pragma unroll
        for (int a = 0; a < SEQ; ++a) {
            float acc = 0.f;
#pragma unroll
            for (int l = 0; l < SEQ; ++l)
                acc = fmaf(ew[a*16 + l], vcr[l], acc);  // broadcast LDS read
            outb[a*64 + lane] = acc;
        }
    }
}

extern "C" void kernel_launch(void* const* d_in, const int* in_sizes, int n_in,
                              void* d_out, int out_size, void* d_ws, size_t ws_size,
                              hipStream_t stream) {
    (void)in_sizes; (void)n_in; (void)out_size; (void)ws_size;
    const float* x   = (const float*)d_in[0];
    const float* wc  = (const float*)d_in[1];
    const float* Wq  = (const float*)d_in[2];
    const float* bq  = (const float*)d_in[3];
    const float* Wk  = (const float*)d_in[4];
    // d_in[5] = bk: provably cancelled by LayerNorm mean-subtraction (constant
    // along the normalized axis after w_c mixing) -> unused.
    const float* Wv  = (const float*)d_in[6];
    const float* bv  = (const float*)d_in[7];
    const float* lng = (const float*)d_in[8];
    const float* lnb = (const float*)d_in[9];
    float* out = (float*)d_out;
    float* ws  = (float*)d_ws;

    prep_kernel<<<dim3(64), dim3(64), 0, stream>>>(Wq, Wk, Wv, bq, ws);
    attn_kernel<<<dim3(2048), dim3(256), 0, stream>>>(x, wc, bv, lng, lnb, ws, out);
}

// Round 2
// 864.502 us; speedup vs baseline: 1.0098x; 1.0098x over previous
//
#include <hip/hip_runtime.h>

#define SEQ 14
#define EMB 64
#define NBC (1024*64)      // B*C = 65536
#define XTILE (SEQ*EMB)    // 896 floats per (b,c) tile
#define LN_EPS 1e-5f
#define WAVES 4
#define XSTR 68            // padded LDS row stride (conflict-free for phase C)

// ---------------------------------------------------------------------------
// prep: M[d][e] = sum_t Wq[t][d]*Wk[t][e]   (so energy = x M x^T + ...)
//       WvT[d][e] = Wv[e][d]
//       r[e] = sum_t bq[t]*Wk[t][e]         (bk-terms cancel under LayerNorm)
// ws layout (floats): interleaved MW[d][e] = (M, WvT) pairs: 64*64*2 = 8192,
//                     then r at [8192..8255]
// ---------------------------------------------------------------------------
__global__ void prep_kernel(const float* __restrict__ Wq, const float* __restrict__ Wk,
                            const float* __restrict__ Wv, const float* __restrict__ bq,
                            float* __restrict__ ws) {
    int d = blockIdx.x;    // 0..63
    int e = threadIdx.x;   // 0..63
    float m = 0.f, r = 0.f;
#pragma unroll 8
    for (int t = 0; t < 64; ++t) {
        float wk = Wk[t*64 + e];
        m = fmaf(Wq[t*64 + d], wk, m);
        r = fmaf(bq[t], wk, r);
    }
    ws[d*128 + 2*e]     = m;               // M[d][e]
    ws[d*128 + 2*e + 1] = Wv[e*64 + d];    // WvT[d][e]
    if (d == 0) ws[8192 + e] = r;
}

// ---------------------------------------------------------------------------
// main: one wave per (b,c) pair, grid-stride. MW lives in LDS (loaded once per
// block); x is read from global exactly once (software-pipelined prefetch);
// all per-bc traffic is LDS. No block barriers in the hot loop.
// ---------------------------------------------------------------------------
__global__ __launch_bounds__(256, 2)
void attn_kernel(const float* __restrict__ x, const float* __restrict__ wc,
                 const float* __restrict__ bv, const float* __restrict__ lng,
                 const float* __restrict__ lnb, const float* __restrict__ ws,
                 float* __restrict__ out) {
    __shared__ __align__(16) float LMW[8192];            // 32 KB (M,WvT) interleaved
    __shared__ __align__(16) float Lwc[14*16];           // w_c rows, stride 16, zero-pad
    __shared__ __align__(16) float Lln[2*16];            // ln_g, ln_b
    __shared__ __align__(16) float LxW[WAVES][SEQ*XSTR]; // per-wave x tile [q][d]
    __shared__ __align__(16) float LgW[WAVES][SEQ*XSTR]; // per-wave g tile [a][d]
    __shared__ __align__(16) float LeW[WAVES][SEQ*16];   // per-wave energy1/att [a][l]

    int tid = threadIdx.x;

    // ---- block-cooperative: stage MW (32 KB) into LDS, coalesced ----
    {
        const float4* src = (const float4*)ws;
        float4* dst = (float4*)LMW;
#pragma unroll
        for (int i = 0; i < 8; ++i)
            dst[tid + 256*i] = src[tid + 256*i];
    }
    if (tid < 224) {
        int a = tid >> 4, m = tid & 15;
        Lwc[tid] = (m < 14) ? wc[a*14 + m] : 0.f;
    }
    if (tid < 16) {
        Lln[tid]      = (tid < 14) ? lng[tid] : 0.f;
        Lln[16 + tid] = (tid < 14) ? lnb[tid] : 0.f;
    }
    __syncthreads();   // only block barrier in the kernel

    int lane = tid & 63;
    int wv   = __builtin_amdgcn_readfirstlane(tid >> 6);
    int wv0  = blockIdx.x * WAVES + wv;
    const int TW = gridDim.x * WAVES;

    float rv  = ws[8192 + lane];   // r[e]
    float bvv = bv[lane];          // v bias

    float* xw = &LxW[wv][0];
    float* gw = &LgW[wv][0];
    float* ew = &LeW[wv][0];

    // LDS write addresses for the staged tile (padded [q][d] layout)
    int i0 = lane, i1 = 64 + lane, i2 = 128 + lane, i3 = 192 + lane;
    float* w0 = xw + (i0 >> 4)*XSTR + (i0 & 15)*4;
    float* w1 = xw + (i1 >> 4)*XSTR + (i1 & 15)*4;
    float* w2 = xw + (i2 >> 4)*XSTR + (i2 & 15)*4;
    float* w3 = xw + (i3 >> 4)*XSTR + (i3 & 15)*4;

    // ---- prologue: prefetch first tile into registers ----
    float4 pf0, pf1, pf2, pf3;
    {
        const float4* xb4 = (const float4*)(x + (size_t)wv0 * XTILE);
        pf0 = xb4[i0];
        pf1 = xb4[i1];
        pf2 = xb4[i2];
        if (lane < 32) pf3 = xb4[i3];
    }

    for (int bc = wv0; bc < NBC; bc += TW) {
        // ---- commit prefetched tile to LDS; immediately prefetch next ----
        *(float4*)w0 = pf0;
        *(float4*)w1 = pf1;
        *(float4*)w2 = pf2;
        if (lane < 32) *(float4*)w3 = pf3;

        int bcn = bc + TW;
        if (bcn < NBC) {
            const float4* xn4 = (const float4*)(x + (size_t)bcn * XTILE);
            pf0 = xn4[i0];
            pf1 = xn4[i1];
            pf2 = xn4[i2];
            if (lane < 32) pf3 = xn4[i3];
        }

        // ---- phase A: t'[i][lane] = x[i][:]·M[:][lane] + r
        //               v [i][lane] = x[i][:]·WvT[:][lane] + bv
        //      x from LDS broadcast b128, MW from LDS b64 (conflict-free) ----
        float tc[SEQ], vcr[SEQ];
#pragma unroll
        for (int i = 0; i < SEQ; ++i) { tc[i] = rv; vcr[i] = bvv; }

        for (int d0 = 0; d0 < 16; ++d0) {
            float4 xs4[SEQ];
#pragma unroll
            for (int i = 0; i < SEQ; ++i)
                xs4[i] = *(const float4*)(xw + i*XSTR + d0*4);   // broadcast read
#pragma unroll
            for (int j = 0; j < 4; ++j) {
                float2 mw = *(const float2*)(&LMW[(d0*4 + j)*128 + 2*lane]);
#pragma unroll
                for (int i = 0; i < SEQ; ++i) {
                    float xv = ((const float*)&xs4[i])[j];
                    tc[i]  = fmaf(xv, mw.x, tc[i]);
                    vcr[i] = fmaf(xv, mw.y, vcr[i]);
                }
            }
        }

        // ---- phase B: g[a][lane] = sum_m wc[a][m] * t'[m][lane] ----
#pragma unroll
        for (int a = 0; a < SEQ; ++a) {
            float acc = 0.f;
#pragma unroll
            for (int m = 0; m < SEQ; ++m)
                acc = fmaf(Lwc[a*16 + m], tc[m], acc);  // broadcast LDS read
            gw[a*XSTR + lane] = acc;
        }

        // ---- phase C: energy1[a][l] = g[a][:]·x[l][:] (196 dots, ~3/lane) ----
#pragma unroll
        for (int k = 0; k < 4; ++k) {
            int p = lane + 64*k;
            if (p < 196) {
                int a = p / 14, l = p % 14;
                float acc = 0.f;
#pragma unroll
                for (int d = 0; d < 64; d += 4) {
                    float4 g4 = *(const float4*)(gw + a*XSTR + d);
                    float4 x4 = *(const float4*)(xw + l*XSTR + d);
                    acc = fmaf(g4.x, x4.x, acc);
                    acc = fmaf(g4.y, x4.y, acc);
                    acc = fmaf(g4.z, x4.z, acc);
                    acc = fmaf(g4.w, x4.w, acc);
                }
                ew[a*16 + l] = acc;
            }
        }

        // ---- phase D: LayerNorm(14) + softmax per row (lane a < 14) ----
        if (lane < SEQ) {
            float ev[SEQ];
            float mu = 0.f;
#pragma unroll
            for (int l = 0; l < SEQ; ++l) { ev[l] = ew[lane*16 + l]; mu += ev[l]; }
            mu *= (1.f/14.f);
            float var = 0.f;
#pragma unroll
            for (int l = 0; l < SEQ; ++l) { float d = ev[l] - mu; var = fmaf(d, d, var); }
            var *= (1.f/14.f);
            float inv = rsqrtf(var + LN_EPS);
            float zmax = -1e30f;
#pragma unroll
            for (int l = 0; l < SEQ; ++l) {
                float z = fmaf((ev[l] - mu) * inv, Lln[l], Lln[16 + l]) * 0.125f; // /sqrt(64)
                ev[l] = z;
                zmax = fmaxf(zmax, z);
            }
            float s = 0.f;
#pragma unroll
            for (int l = 0; l < SEQ; ++l) { float e = __expf(ev[l] - zmax); ev[l] = e; s += e; }
            float rs = 1.f / s;
#pragma unroll
            for (int l = 0; l < SEQ; ++l) ew[lane*16 + l] = ev[l] * rs;
        }

        // ---- phase E: out[a][lane] = sum_l att[a][l] * v[l][lane] ----
        float* outb = out + (size_t)bc * XTILE;
#pragma unroll
        for (int a = 0; a < SEQ; ++a) {
            float acc = 0.f;
#pragma unroll
            for (int l = 0; l < SEQ; ++l)
                acc = fmaf(ew[a*16 + l], vcr[l], acc);  // broadcast LDS read
            outb[a*64 + lane] = acc;
        }
    }
}

extern "C" void kernel_launch(void* const* d_in, const int* in_sizes, int n_in,
                              void* d_out, int out_size, void* d_ws, size_t ws_size,
                              hipStream_t stream) {
    (void)in_sizes; (void)n_in; (void)out_size; (void)ws_size;
    const float* x   = (const float*)d_in[0];
    const float* wc  = (const float*)d_in[1];
    const float* Wq  = (const float*)d_in[2];
    const float* bq  = (const float*)d_in[3];
    const float* Wk  = (const float*)d_in[4];
    // d_in[5] = bk: cancelled by LayerNorm mean-subtraction -> unused.
    const float* Wv  = (const float*)d_in[6];
    const float* bv  = (const float*)d_in[7];
    const float* lng = (const float*)d_in[8];
    const float* lnb = (const float*)d_in[9];
    float* out = (float*)d_out;
    float* ws  = (float*)d_ws;

    prep_kernel<<<dim3(64), dim3(64), 0, stream>>>(Wq, Wk, Wv, bq, ws);
    attn_kernel<<<dim3(2048), dim3(256), 0, stream>>>(x, wc, bv, lng, lnb, ws, out);
}